// Round 13
// baseline (264.165 us; speedup 1.0000x reference)
//
#include <hip/hip_runtime.h>
#include <math.h>

#define HD 64
#define KVBLK 64
#define LP 72

typedef __attribute__((ext_vector_type(8))) short short8;
typedef __attribute__((ext_vector_type(4))) short short4v;
typedef __attribute__((ext_vector_type(4))) float f32x4;

__device__ __forceinline__ short f2bf(float f) {
    union { float f; unsigned u; } in;
    in.f = f;
    unsigned r = (in.u + 0x7fff + ((in.u >> 16) & 1)) >> 16;  // RNE
    return (short)r;
}

// ---------------- fp32 -> bf16 convert ----------------
__global__ __launch_bounds__(256) void convert_bf16(const float* __restrict__ in,
                                                    short* __restrict__ out, long n4) {
    long i = blockIdx.x * 256L + threadIdx.x;
    if (i >= n4) return;
    float4 v = reinterpret_cast<const float4*>(in)[i];
    short4v o;
    o[0] = f2bf(v.x); o[1] = f2bf(v.y); o[2] = f2bf(v.z); o[3] = f2bf(v.w);
    reinterpret_cast<short4v*>(out)[i] = o;
}

// ------------- transpose + convert: [K][N] fp32 -> [N][K] bf16 -------------
__global__ __launch_bounds__(256) void transpose_bf16(const float* __restrict__ in,
                                                      short* __restrict__ out, int K, int N) {
    __shared__ float tile[32][33];
    const int n0 = blockIdx.x * 32, k0 = blockIdx.y * 32;
    const int tx = threadIdx.x & 31, ty = threadIdx.x >> 5;
    #pragma unroll
    for (int i = ty; i < 32; i += 8)
        tile[i][tx] = in[(size_t)(k0 + i) * N + n0 + tx];
    __syncthreads();
    #pragma unroll
    for (int i = ty; i < 32; i += 8)
        out[(size_t)(n0 + i) * K + k0 + tx] = f2bf(tile[tx][i]);
}

// ------- V pre-transpose: qkv V-part [b][key][h][d] -> vT[(b*H+h)][d][key640] -------
__global__ __launch_bounds__(256) void transpose_v(const short* __restrict__ qkvb,
                                                   short* __restrict__ vT) {
    constexpr int Nn = 577, C3 = 2304, NH = 12, NKP = 640;
    const int bh = blockIdx.x;
    const int kt = blockIdx.y;
    const int b = bh / NH, h = bh % NH;
    const int tid = threadIdx.x;
    __shared__ short tile[64][33];

    const int tk = tid >> 3;
    const int key = kt * 32 + tk;
    const int d0 = (tid & 7) * 8;
    short8 v = {0, 0, 0, 0, 0, 0, 0, 0};
    if (key < Nn)
        v = *reinterpret_cast<const short8*>(
            qkvb + (size_t)(b * Nn + key) * C3 + 1536 + h * 64 + d0);
    #pragma unroll
    for (int i = 0; i < 8; ++i) tile[d0 + i][tk] = v[i];
    __syncthreads();

    const int d = tid >> 2;
    const int kb = (tid & 3) * 8;
    short8 o;
    #pragma unroll
    for (int i = 0; i < 8; ++i) o[i] = tile[d][kb + i];
    *reinterpret_cast<short8*>(vT + (size_t)(bh * 64 + d) * NKP + kt * 32 + kb) = o;
}

// ------- bf16 MFMA GEMM: 128x128, BK=32, 3-buf depth-2 prefetch, counted vmcnt (T4) -------
// Never drains vmcnt to 0 in the main loop: stage(t+2) issued at step top (4 loads/thread),
// step end does vmcnt(4) (tile t+1 landed, t+2 in flight) + raw s_barrier.
// LDS 48KB -> 3 blocks/CU. T2 XOR swizzle as in r11 (packed row-pairs, both-sides involution).
template <typename OutT>
__global__ __launch_bounds__(256) void gemm_bf16(const short* __restrict__ A,
                                                 const short* __restrict__ Bt,
                                                 const float* __restrict__ bias,
                                                 OutT* __restrict__ C,
                                                 int M, int N, int K, int nbn) {
    __shared__ short As[3][64 * 64];
    __shared__ short Bs[3][64 * 64];
    const int tid = threadIdx.x;
    const int w = tid >> 6, lane = tid & 63;
    const int g = lane >> 4, l16 = lane & 15;

    // bijective XCD swizzle (m204), bm-major: each XCD owns contiguous row-bands
    const int nwg = gridDim.x;
    const int q = nwg >> 3, r = nwg & 7;
    const int xcd = blockIdx.x & 7, loc = blockIdx.x >> 3;
    const int wgid = (xcd < r ? xcd * (q + 1) : r * (q + 1) + (xcd - r) * q) + loc;
    const int bm = wgid / nbn, bn = wgid % nbn;
    const int m0 = bm * 128, n0 = bn * 128;
    const int wm = (w >> 1) * 64, wn = (w & 1) * 64;

    f32x4 acc[4][4] = {};
    const int NT = K >> 5;   // BK=32

    // staging: 4 global_load_lds per thread (2 for A, 2 for B)
    auto stage = [&](int buf, int k0) {
        #pragma unroll
        for (int j = 0; j < 2; ++j) {
            const int o = j * 4096 + tid * 16;          // LDS byte offset
            const int R = o >> 7;                       // packed LDS row
            const int sl = ((o >> 4) & 7) ^ (R & 7);    // logical slot (inverse swizzle)
            const int rr = 2 * R + (sl >> 2);           // source matrix row in tile
            const int cblk = sl & 3;                    // source col block (8 elems)
            long arow = m0 + rr; if (arow > M - 1) arow = M - 1;
            const short* ga = A + arow * K + k0 + cblk * 8;
            const short* gb = Bt + (size_t)(n0 + rr) * K + k0 + cblk * 8;
            __builtin_amdgcn_global_load_lds(
                (const __attribute__((address_space(1))) unsigned*)ga,
                (__attribute__((address_space(3))) unsigned*)((char*)&As[buf][0] + o),
                16, 0, 0);
            __builtin_amdgcn_global_load_lds(
                (const __attribute__((address_space(1))) unsigned*)gb,
                (__attribute__((address_space(3))) unsigned*)((char*)&Bs[buf][0] + o),
                16, 0, 0);
        }
    };

    // prologue: tiles 0 and 1 in flight; wait tile 0 (leave tile 1 flying)
    stage(0, 0);
    if (NT > 1) stage(1, 32);
    asm volatile("s_waitcnt vmcnt(4)" ::: "memory");
    __builtin_amdgcn_s_barrier();
    __builtin_amdgcn_sched_barrier(0);

    for (int kt = 0; kt < NT; ++kt) {
        const int cur = kt % 3;
        if (kt + 2 < NT) stage((kt + 2) % 3, (kt + 2) * 32);   // issue-early, 2 steps ahead

        short8 af[4], bfr[4];
        #pragma unroll
        for (int mi = 0; mi < 4; ++mi) {
            const int ra = wm + mi * 16 + l16;
            const int Ra = ra >> 1;
            const int sla = (4 * (ra & 1) + g) ^ (Ra & 7);
            af[mi] = *reinterpret_cast<const short8*>(&As[cur][Ra * 64 + sla * 8]);
        }
        #pragma unroll
        for (int ni = 0; ni < 4; ++ni) {
            const int rb = wn + ni * 16 + l16;
            const int Rb = rb >> 1;
            const int slb = (4 * (rb & 1) + g) ^ (Rb & 7);
            bfr[ni] = *reinterpret_cast<const short8*>(&Bs[cur][Rb * 64 + slb * 8]);
        }
        __builtin_amdgcn_s_setprio(1);
        #pragma unroll
        for (int mi = 0; mi < 4; ++mi)
            #pragma unroll
            for (int ni = 0; ni < 4; ++ni)
                acc[mi][ni] = __builtin_amdgcn_mfma_f32_16x16x32_bf16(
                    af[mi], bfr[ni], acc[mi][ni], 0, 0, 0);
        __builtin_amdgcn_s_setprio(0);

        // counted drain: tile t+1's 4 loads land; t+2's 4 stay in flight
        if (kt + 2 < NT) asm volatile("s_waitcnt vmcnt(4)" ::: "memory");
        else             asm volatile("s_waitcnt vmcnt(0)" ::: "memory");
        __builtin_amdgcn_s_barrier();
        __builtin_amdgcn_sched_barrier(0);
    }

    float bv[4];
    #pragma unroll
    for (int ni = 0; ni < 4; ++ni) bv[ni] = bias[n0 + wn + ni * 16 + l16];
    #pragma unroll
    for (int mi = 0; mi < 4; ++mi) {
        #pragma unroll
        for (int rr = 0; rr < 4; ++rr) {
            const int row = m0 + wm + mi * 16 + g * 4 + rr;
            if (row < M) {
                #pragma unroll
                for (int ni = 0; ni < 4; ++ni) {
                    float val = acc[mi][ni][rr] + bv[ni];
                    if constexpr (__is_same(OutT, float))
                        C[(size_t)row * N + n0 + wn + ni * 16 + l16] = val;
                    else
                        C[(size_t)row * N + n0 + wn + ni * 16 + l16] = f2bf(val);
                }
            }
        }
    }
}

// ------- flash attention: swapped-QK^T, K and V via global_load_lds -------
__global__ __launch_bounds__(256) void flash_attn(const short* __restrict__ qkvb,
                                                  const short* __restrict__ vT,
                                                  const float* __restrict__ scale,
                                                  short* __restrict__ out) {
    constexpr int Nn = 577, Cc = 768, C3 = 2304, NQB = 10, NH = 12, NT = 10, NKP = 640;
    const int bid = blockIdx.x;
    const int swz = (bid & 7) * 480 + (bid >> 3);
    const int q0 = (swz % NQB) * 64;
    const int h  = (swz / NQB) % NH;
    const int b  = swz / (NQB * NH);
    const int qblk = q0 >> 6;

    const int tid  = threadIdx.x;
    const int w    = tid >> 6;
    const int lane = tid & 63;
    const int g    = lane >> 4;
    const int l16  = lane & 15;

    __shared__ alignas(16) short Ks[2][KVBLK * HD];
    __shared__ alignas(16) short Vts[2][HD * KVBLK];
    __shared__ alignas(16) short Ps[4][16][LP];

    const float sl2 = scale[h] * 1.44269504088896f;
    const float thr = 8.0f / sl2;
    const short* base = qkvb + (size_t)b * Nn * C3;
    const short* kglob = base + Cc + h * HD;
    const short* vtb = vT + (size_t)(b * NH + h) * HD * NKP;

    const int qrow = q0 + w * 16 + l16;
    const int qr = qrow < Nn ? qrow : Nn - 1;
    const short* qp = base + (size_t)qr * C3 + h * HD;
    short8 aq[2];
    aq[0] = *reinterpret_cast<const short8*>(qp + 8 * g);
    aq[1] = *reinterpret_cast<const short8*>(qp + 32 + 8 * g);

    f32x4 oacc[4] = {};
    float mrun = -INFINITY, m2 = -INFINITY, lrun = 0.f;

    const int kst_row = lane >> 3;
    const int kst_dblk = (lane & 7) ^ (lane >> 3);

    auto stageK = [&](int bufi, int kv0) {
        #pragma unroll
        for (int t = 0; t < 2; ++t) {
            const int i = 2 * w + t;
            int kr = kv0 + 8 * i + kst_row;
            if (kr > Nn - 1) kr = Nn - 1;
            const short* src = kglob + (size_t)kr * C3 + kst_dblk * 8;
            __builtin_amdgcn_global_load_lds(
                (const __attribute__((address_space(1))) unsigned*)src,
                (__attribute__((address_space(3))) unsigned*)&Ks[bufi][i * 512],
                16, 0, 0);
        }
    };
    auto stageV = [&](int bufi, int kv0) {
        #pragma unroll
        for (int t = 0; t < 2; ++t) {
            const int i = 2 * w + t;
            const int r = 8 * i + kst_row;
            const int kb = (lane & 7) ^ (r & 7);
            const short* src = vtb + (size_t)r * NKP + kv0 + kb * 8;
            __builtin_amdgcn_global_load_lds(
                (const __attribute__((address_space(1))) unsigned*)src,
                (__attribute__((address_space(3))) unsigned*)&Vts[bufi][i * 512],
                16, 0, 0);
        }
    };

    stageK(0, 0);
    stageV(0, 0);
    __syncthreads();

    for (int t = 0; t < NT; ++t) {
        const int cur = t & 1, nxt = cur ^ 1;
        const int kv0 = t * KVBLK;
        const bool more = (t + 1 < NT);
        if (more) { stageK(nxt, kv0 + KVBLK); stageV(nxt, kv0 + KVBLK); }

        f32x4 sacc[4] = {};
        __builtin_amdgcn_s_setprio(1);
        #pragma unroll
        for (int f = 0; f < 4; ++f) {
            #pragma unroll
            for (int c = 0; c < 2; ++c) {
                const int slot = (4 * c + g) ^ (l16 & 7);
                short8 ak = *reinterpret_cast<const short8*>(
                    &Ks[cur][(16 * f + l16) * 64 + slot * 8]);
                sacc[f] = __builtin_amdgcn_mfma_f32_16x16x32_bf16(ak, aq[c], sacc[f], 0, 0, 0);
            }
        }
        __builtin_amdgcn_s_setprio(0);

        const int ig = q0 + w * 16 + l16;
        float s2[4][4];
        #pragma unroll
        for (int f = 0; f < 4; ++f)
            #pragma unroll
            for (int r = 0; r < 4; ++r)
                s2[f][r] = sacc[f][r];
        if (t == qblk || t == NT - 1) {
            #pragma unroll
            for (int f = 0; f < 4; ++f)
                #pragma unroll
                for (int r = 0; r < 4; ++r) {
                    const int jg = kv0 + 16 * f + 4 * g + r;
                    if (jg >= Nn || (jg == ig && ig >= 1)) s2[f][r] = -INFINITY;
                }
        }

        float mx = s2[0][0];
        #pragma unroll
        for (int f = 0; f < 4; ++f)
            #pragma unroll
            for (int r = 0; r < 4; ++r)
                if (f + r) mx = fmaxf(mx, s2[f][r]);
        mx = fmaxf(mx, __shfl_xor(mx, 16, 64));
        mx = fmaxf(mx, __shfl_xor(mx, 32, 64));

        if (__any(mx > mrun + thr)) {
            const float mnew = fmaxf(mrun, mx);
            const float m2new = mnew * sl2;
            const float fac = __builtin_amdgcn_exp2f(m2 - m2new);
            mrun = mnew; m2 = m2new;
            lrun *= fac;
            #pragma unroll
            for (int r = 0; r < 4; ++r) {
                const float fr = __shfl(fac, 16 * g + 4 * g + r, 64);  // lane with l16 == 4g+r
                #pragma unroll
                for (int df = 0; df < 4; ++df) oacc[df][r] *= fr;
            }
        }

        float sum = 0.f;
        #pragma unroll
        for (int f = 0; f < 4; ++f)
            #pragma unroll
            for (int r = 0; r < 4; ++r) {
                float p = __builtin_amdgcn_exp2f(fmaf(s2[f][r], sl2, -m2));
                s2[f][r] = p;
                sum += p;
            }
        sum += __shfl_xor(sum, 16, 64);
        sum += __shfl_xor(sum, 32, 64);
        lrun += sum;

        #pragma unroll
        for (int f = 0; f < 4; ++f) {
            unsigned plo, phi;
            asm("v_cvt_pk_bf16_f32 %0, %1, %2" : "=v"(plo) : "v"(s2[f][0]), "v"(s2[f][1]));
            asm("v_cvt_pk_bf16_f32 %0, %1, %2" : "=v"(phi) : "v"(s2[f][2]), "v"(s2[f][3]));
            unsigned* dst = reinterpret_cast<unsigned*>(&Ps[w][l16][16 * f + 4 * g]);
            dst[0] = plo; dst[1] = phi;
        }
        asm volatile("s_waitcnt lgkmcnt(0)" ::: "memory");

        __builtin_amdgcn_s_setprio(1);
        #pragma unroll
        for (int c = 0; c < 2; ++c) {
            short8 pa = *reinterpret_cast<const short8*>(&Ps[w][l16][32 * c + 8 * g]);
            #pragma unroll
            for (int df = 0; df < 4; ++df) {
                const int slot = (4 * c + g) ^ (l16 & 7);
                short8 bv = *reinterpret_cast<const short8*>(
                    &Vts[cur][(16 * df + l16) * 64 + slot * 8]);
                oacc[df] = __builtin_amdgcn_mfma_f32_16x16x32_bf16(pa, bv, oacc[df], 0, 0, 0);
            }
        }
        __builtin_amdgcn_s_setprio(0);
        __syncthreads();
    }

    #pragma unroll
    for (int r = 0; r < 4; ++r) {
        const int og = q0 + w * 16 + g * 4 + r;
        if (og < Nn) {
            const float lr_r = __shfl(lrun, 16 * g + 4 * g + r, 64);
            const float inv = 1.f / lr_r;
            #pragma unroll
            for (int df = 0; df < 4; ++df)
                out[(size_t)(b * Nn + og) * Cc + h * HD + 16 * df + l16] =
                    f2bf(oacc[df][r] * inv);
        }
    }
}

extern "C" void kernel_launch(void* const* d_in, const int* in_sizes, int n_in,
                              void* d_out, int out_size, void* d_ws, size_t ws_size,
                              hipStream_t stream) {
    const float* x      = (const float*)d_in[0];
    const float* w_qkv  = (const float*)d_in[1];
    const float* b_qkv  = (const float*)d_in[2];
    const float* scale  = (const float*)d_in[3];
    const float* w_proj = (const float*)d_in[4];
    const float* b_proj = (const float*)d_in[5];
    float* out = (float*)d_out;

    const int B = 32, N = 577, C = 768, H = 12;
    const int M  = B * N;     // 18464
    const int C3 = 3 * C;     // 2304
    const int MB = (M + 127) / 128;   // 145

    short* qkvb   = (short*)d_ws;
    short* attn_o = qkvb + (size_t)M * C3;
    short* xb     = attn_o + (size_t)M * C;
    short* wqkvT  = xb + (size_t)M * C;
    short* wprojT = wqkvT + (size_t)C3 * C;
    short* vT     = wprojT + (size_t)C * C;

    dim3 blk(256);
    const long n4 = (long)M * C / 4;
    convert_bf16<<<dim3((n4 + 255) / 256), blk, 0, stream>>>(x, xb, n4);
    transpose_bf16<<<dim3(C3 / 32, C / 32), blk, 0, stream>>>(w_qkv, wqkvT, C, C3);
    transpose_bf16<<<dim3(C / 32, C / 32), blk, 0, stream>>>(w_proj, wprojT, C, C);

    gemm_bf16<short><<<dim3(MB * (C3 / 128)), blk, 0, stream>>>(
        xb, wqkvT, b_qkv, qkvb, M, C3, C, C3 / 128);

    transpose_v<<<dim3(B * H, 20), blk, 0, stream>>>(qkvb, vT);

    flash_attn<<<dim3(((N + 63) / 64) * H * B), blk, 0, stream>>>(qkvb, vT, scale, attn_o);

    gemm_bf16<float><<<dim3(MB * (C / 128)), blk, 0, stream>>>(
        attn_o, wprojT, b_proj, out, M, C, C, C / 128);
}

// Round 14
// 247.113 us; speedup vs baseline: 1.0690x; 1.0690x over previous
//
#include <hip/hip_runtime.h>
#include <math.h>

#define HD 64
#define KVBLK 64
#define LP 72

typedef __attribute__((ext_vector_type(8))) short short8;
typedef __attribute__((ext_vector_type(4))) short short4v;
typedef __attribute__((ext_vector_type(4))) float f32x4;

__device__ __forceinline__ short f2bf(float f) {
    union { float f; unsigned u; } in;
    in.f = f;
    unsigned r = (in.u + 0x7fff + ((in.u >> 16) & 1)) >> 16;  // RNE
    return (short)r;
}

// ---------------- fp32 -> bf16 convert ----------------
__global__ __launch_bounds__(256) void convert_bf16(const float* __restrict__ in,
                                                    short* __restrict__ out, long n4) {
    long i = blockIdx.x * 256L + threadIdx.x;
    if (i >= n4) return;
    float4 v = reinterpret_cast<const float4*>(in)[i];
    short4v o;
    o[0] = f2bf(v.x); o[1] = f2bf(v.y); o[2] = f2bf(v.z); o[3] = f2bf(v.w);
    reinterpret_cast<short4v*>(out)[i] = o;
}

// ------------- transpose + convert: [K][N] fp32 -> [N][K] bf16 -------------
__global__ __launch_bounds__(256) void transpose_bf16(const float* __restrict__ in,
                                                      short* __restrict__ out, int K, int N) {
    __shared__ float tile[32][33];
    const int n0 = blockIdx.x * 32, k0 = blockIdx.y * 32;
    const int tx = threadIdx.x & 31, ty = threadIdx.x >> 5;
    #pragma unroll
    for (int i = ty; i < 32; i += 8)
        tile[i][tx] = in[(size_t)(k0 + i) * N + n0 + tx];
    __syncthreads();
    #pragma unroll
    for (int i = ty; i < 32; i += 8)
        out[(size_t)(n0 + i) * K + k0 + tx] = f2bf(tile[tx][i]);
}

// ------- V pre-transpose: qkv V-part [b][key][h][d] -> vT[(b*H+h)][d][key640] -------
__global__ __launch_bounds__(256) void transpose_v(const short* __restrict__ qkvb,
                                                   short* __restrict__ vT) {
    constexpr int Nn = 577, C3 = 2304, NH = 12, NKP = 640;
    const int bh = blockIdx.x;
    const int kt = blockIdx.y;
    const int b = bh / NH, h = bh % NH;
    const int tid = threadIdx.x;
    __shared__ short tile[64][33];

    const int tk = tid >> 3;
    const int key = kt * 32 + tk;
    const int d0 = (tid & 7) * 8;
    short8 v = {0, 0, 0, 0, 0, 0, 0, 0};
    if (key < Nn)
        v = *reinterpret_cast<const short8*>(
            qkvb + (size_t)(b * Nn + key) * C3 + 1536 + h * 64 + d0);
    #pragma unroll
    for (int i = 0; i < 8; ++i) tile[d0 + i][tk] = v[i];
    __syncthreads();

    const int d = tid >> 2;
    const int kb = (tid & 3) * 8;
    short8 o;
    #pragma unroll
    for (int i = 0; i < 8; ++i) o[i] = tile[d][kb + i];
    *reinterpret_cast<short8*>(vT + (size_t)(bh * 64 + d) * NKP + kt * 32 + kb) = o;
}

// ------- bf16 MFMA GEMM: 256x128 block tile, 8x4 per-wave blocking, BK=32 -------
// Wave tile 128x64: 12 frag-reads per 32 MFMA (384 B/MFMA, -25% LDS vs 4x4).
// 2-buf LDS (48KB), single __syncthreads per K-step (r12 proven loop).
// Packed-pair XOR swizzle (r11, conflict-free both sides). XCD row-band swizzle.
template <typename OutT>
__global__ __launch_bounds__(256, 2) void gemm_bf16(const short* __restrict__ A,
                                                    const short* __restrict__ Bt,
                                                    const float* __restrict__ bias,
                                                    OutT* __restrict__ C,
                                                    int M, int N, int K, int nbn) {
    __shared__ short As[2][128 * 64];   // 256 rows packed in pairs
    __shared__ short Bs[2][64 * 64];    // 128 rows packed in pairs
    const int tid = threadIdx.x;
    const int w = tid >> 6, lane = tid & 63;
    const int g = lane >> 4, l16 = lane & 15;

    const int nwg = gridDim.x;
    const int q = nwg >> 3, r = nwg & 7;
    const int xcd = blockIdx.x & 7, loc = blockIdx.x >> 3;
    const int wgid = (xcd < r ? xcd * (q + 1) : r * (q + 1) + (xcd - r) * q) + loc;
    const int bm = wgid / nbn, bn = wgid % nbn;
    const int m0 = bm * 256, n0 = bn * 128;
    const int wm = (w >> 1) * 128, wn = (w & 1) * 64;   // 2x2 waves, wave tile 128x64

    f32x4 acc[8][4] = {};
    const int NT = K >> 5;   // BK=32

    auto stage = [&](int buf, int k0) {
        // A: 256x32 = 16KB = 4 insts; B: 128x32 = 8KB = 2 insts
        #pragma unroll
        for (int j = 0; j < 4; ++j) {
            const int o = j * 4096 + tid * 16;
            const int R = o >> 7;
            const int sl = ((o >> 4) & 7) ^ (R & 7);
            const int rr = 2 * R + (sl >> 2);
            const int cblk = sl & 3;
            long arow = m0 + rr; if (arow > M - 1) arow = M - 1;
            const short* ga = A + arow * K + k0 + cblk * 8;
            __builtin_amdgcn_global_load_lds(
                (const __attribute__((address_space(1))) unsigned*)ga,
                (__attribute__((address_space(3))) unsigned*)((char*)&As[buf][0] + o),
                16, 0, 0);
        }
        #pragma unroll
        for (int j = 0; j < 2; ++j) {
            const int o = j * 4096 + tid * 16;
            const int R = o >> 7;
            const int sl = ((o >> 4) & 7) ^ (R & 7);
            const int rr = 2 * R + (sl >> 2);
            const int cblk = sl & 3;
            const short* gb = Bt + (size_t)(n0 + rr) * K + k0 + cblk * 8;
            __builtin_amdgcn_global_load_lds(
                (const __attribute__((address_space(1))) unsigned*)gb,
                (__attribute__((address_space(3))) unsigned*)((char*)&Bs[buf][0] + o),
                16, 0, 0);
        }
    };

    stage(0, 0);
    __syncthreads();

    for (int kt = 0; kt < NT; ++kt) {
        const int cur = kt & 1;
        if (kt + 1 < NT) stage(cur ^ 1, (kt + 1) * 32);

        short8 af[8], bfr[4];
        #pragma unroll
        for (int mi = 0; mi < 8; ++mi) {
            const int ra = wm + mi * 16 + l16;
            const int Ra = ra >> 1;
            const int sla = (4 * (ra & 1) + g) ^ (Ra & 7);
            af[mi] = *reinterpret_cast<const short8*>(&As[cur][Ra * 64 + sla * 8]);
        }
        #pragma unroll
        for (int ni = 0; ni < 4; ++ni) {
            const int rb = wn + ni * 16 + l16;
            const int Rb = rb >> 1;
            const int slb = (4 * (rb & 1) + g) ^ (Rb & 7);
            bfr[ni] = *reinterpret_cast<const short8*>(&Bs[cur][Rb * 64 + slb * 8]);
        }
        __builtin_amdgcn_s_setprio(1);
        #pragma unroll
        for (int mi = 0; mi < 8; ++mi)
            #pragma unroll
            for (int ni = 0; ni < 4; ++ni)
                acc[mi][ni] = __builtin_amdgcn_mfma_f32_16x16x32_bf16(
                    af[mi], bfr[ni], acc[mi][ni], 0, 0, 0);
        __builtin_amdgcn_s_setprio(0);
        __syncthreads();
    }

    float bv[4];
    #pragma unroll
    for (int ni = 0; ni < 4; ++ni) bv[ni] = bias[n0 + wn + ni * 16 + l16];
    #pragma unroll
    for (int mi = 0; mi < 8; ++mi) {
        #pragma unroll
        for (int rr = 0; rr < 4; ++rr) {
            const int row = m0 + wm + mi * 16 + g * 4 + rr;
            if (row < M) {
                #pragma unroll
                for (int ni = 0; ni < 4; ++ni) {
                    float val = acc[mi][ni][rr] + bv[ni];
                    if constexpr (__is_same(OutT, float))
                        C[(size_t)row * N + n0 + wn + ni * 16 + l16] = val;
                    else
                        C[(size_t)row * N + n0 + wn + ni * 16 + l16] = f2bf(val);
                }
            }
        }
    }
}

// ------- flash attention: swapped-QK^T, K and V via global_load_lds (unchanged) -------
__global__ __launch_bounds__(256) void flash_attn(const short* __restrict__ qkvb,
                                                  const short* __restrict__ vT,
                                                  const float* __restrict__ scale,
                                                  short* __restrict__ out) {
    constexpr int Nn = 577, Cc = 768, C3 = 2304, NQB = 10, NH = 12, NT = 10, NKP = 640;
    const int bid = blockIdx.x;
    const int swz = (bid & 7) * 480 + (bid >> 3);
    const int q0 = (swz % NQB) * 64;
    const int h  = (swz / NQB) % NH;
    const int b  = swz / (NQB * NH);
    const int qblk = q0 >> 6;

    const int tid  = threadIdx.x;
    const int w    = tid >> 6;
    const int lane = tid & 63;
    const int g    = lane >> 4;
    const int l16  = lane & 15;

    __shared__ alignas(16) short Ks[2][KVBLK * HD];
    __shared__ alignas(16) short Vts[2][HD * KVBLK];
    __shared__ alignas(16) short Ps[4][16][LP];

    const float sl2 = scale[h] * 1.44269504088896f;
    const float thr = 8.0f / sl2;
    const short* base = qkvb + (size_t)b * Nn * C3;
    const short* kglob = base + Cc + h * HD;
    const short* vtb = vT + (size_t)(b * NH + h) * HD * NKP;

    const int qrow = q0 + w * 16 + l16;
    const int qr = qrow < Nn ? qrow : Nn - 1;
    const short* qp = base + (size_t)qr * C3 + h * HD;
    short8 aq[2];
    aq[0] = *reinterpret_cast<const short8*>(qp + 8 * g);
    aq[1] = *reinterpret_cast<const short8*>(qp + 32 + 8 * g);

    f32x4 oacc[4] = {};
    float mrun = -INFINITY, m2 = -INFINITY, lrun = 0.f;

    const int kst_row = lane >> 3;
    const int kst_dblk = (lane & 7) ^ (lane >> 3);

    auto stageK = [&](int bufi, int kv0) {
        #pragma unroll
        for (int t = 0; t < 2; ++t) {
            const int i = 2 * w + t;
            int kr = kv0 + 8 * i + kst_row;
            if (kr > Nn - 1) kr = Nn - 1;
            const short* src = kglob + (size_t)kr * C3 + kst_dblk * 8;
            __builtin_amdgcn_global_load_lds(
                (const __attribute__((address_space(1))) unsigned*)src,
                (__attribute__((address_space(3))) unsigned*)&Ks[bufi][i * 512],
                16, 0, 0);
        }
    };
    auto stageV = [&](int bufi, int kv0) {
        #pragma unroll
        for (int t = 0; t < 2; ++t) {
            const int i = 2 * w + t;
            const int r = 8 * i + kst_row;
            const int kb = (lane & 7) ^ (r & 7);
            const short* src = vtb + (size_t)r * NKP + kv0 + kb * 8;
            __builtin_amdgcn_global_load_lds(
                (const __attribute__((address_space(1))) unsigned*)src,
                (__attribute__((address_space(3))) unsigned*)&Vts[bufi][i * 512],
                16, 0, 0);
        }
    };

    stageK(0, 0);
    stageV(0, 0);
    __syncthreads();

    for (int t = 0; t < NT; ++t) {
        const int cur = t & 1, nxt = cur ^ 1;
        const int kv0 = t * KVBLK;
        const bool more = (t + 1 < NT);
        if (more) { stageK(nxt, kv0 + KVBLK); stageV(nxt, kv0 + KVBLK); }

        f32x4 sacc[4] = {};
        __builtin_amdgcn_s_setprio(1);
        #pragma unroll
        for (int f = 0; f < 4; ++f) {
            #pragma unroll
            for (int c = 0; c < 2; ++c) {
                const int slot = (4 * c + g) ^ (l16 & 7);
                short8 ak = *reinterpret_cast<const short8*>(
                    &Ks[cur][(16 * f + l16) * 64 + slot * 8]);
                sacc[f] = __builtin_amdgcn_mfma_f32_16x16x32_bf16(ak, aq[c], sacc[f], 0, 0, 0);
            }
        }
        __builtin_amdgcn_s_setprio(0);

        const int ig = q0 + w * 16 + l16;
        float s2[4][4];
        #pragma unroll
        for (int f = 0; f < 4; ++f)
            #pragma unroll
            for (int r = 0; r < 4; ++r)
                s2[f][r] = sacc[f][r];
        if (t == qblk || t == NT - 1) {
            #pragma unroll
            for (int f = 0; f < 4; ++f)
                #pragma unroll
                for (int r = 0; r < 4; ++r) {
                    const int jg = kv0 + 16 * f + 4 * g + r;
                    if (jg >= Nn || (jg == ig && ig >= 1)) s2[f][r] = -INFINITY;
                }
        }

        float mx = s2[0][0];
        #pragma unroll
        for (int f = 0; f < 4; ++f)
            #pragma unroll
            for (int r = 0; r < 4; ++r)
                if (f + r) mx = fmaxf(mx, s2[f][r]);
        mx = fmaxf(mx, __shfl_xor(mx, 16, 64));
        mx = fmaxf(mx, __shfl_xor(mx, 32, 64));

        if (__any(mx > mrun + thr)) {
            const float mnew = fmaxf(mrun, mx);
            const float m2new = mnew * sl2;
            const float fac = __builtin_amdgcn_exp2f(m2 - m2new);
            mrun = mnew; m2 = m2new;
            lrun *= fac;
            #pragma unroll
            for (int r = 0; r < 4; ++r) {
                const float fr = __shfl(fac, 16 * g + 4 * g + r, 64);
                #pragma unroll
                for (int df = 0; df < 4; ++df) oacc[df][r] *= fr;
            }
        }

        float sum = 0.f;
        #pragma unroll
        for (int f = 0; f < 4; ++f)
            #pragma unroll
            for (int r = 0; r < 4; ++r) {
                float p = __builtin_amdgcn_exp2f(fmaf(s2[f][r], sl2, -m2));
                s2[f][r] = p;
                sum += p;
            }
        sum += __shfl_xor(sum, 16, 64);
        sum += __shfl_xor(sum, 32, 64);
        lrun += sum;

        #pragma unroll
        for (int f = 0; f < 4; ++f) {
            unsigned plo, phi;
            asm("v_cvt_pk_bf16_f32 %0, %1, %2" : "=v"(plo) : "v"(s2[f][0]), "v"(s2[f][1]));
            asm("v_cvt_pk_bf16_f32 %0, %1, %2" : "=v"(phi) : "v"(s2[f][2]), "v"(s2[f][3]));
            unsigned* dst = reinterpret_cast<unsigned*>(&Ps[w][l16][16 * f + 4 * g]);
            dst[0] = plo; dst[1] = phi;
        }
        asm volatile("s_waitcnt lgkmcnt(0)" ::: "memory");

        __builtin_amdgcn_s_setprio(1);
        #pragma unroll
        for (int c = 0; c < 2; ++c) {
            short8 pa = *reinterpret_cast<const short8*>(&Ps[w][l16][32 * c + 8 * g]);
            #pragma unroll
            for (int df = 0; df < 4; ++df) {
                const int slot = (4 * c + g) ^ (l16 & 7);
                short8 bv = *reinterpret_cast<const short8*>(
                    &Vts[cur][(16 * df + l16) * 64 + slot * 8]);
                oacc[df] = __builtin_amdgcn_mfma_f32_16x16x32_bf16(pa, bv, oacc[df], 0, 0, 0);
            }
        }
        __builtin_amdgcn_s_setprio(0);
        __syncthreads();
    }

    #pragma unroll
    for (int r = 0; r < 4; ++r) {
        const int og = q0 + w * 16 + g * 4 + r;
        if (og < Nn) {
            const float lr_r = __shfl(lrun, 16 * g + 4 * g + r, 64);
            const float inv = 1.f / lr_r;
            #pragma unroll
            for (int df = 0; df < 4; ++df)
                out[(size_t)(b * Nn + og) * Cc + h * HD + 16 * df + l16] =
                    f2bf(oacc[df][r] * inv);
        }
    }
}

extern "C" void kernel_launch(void* const* d_in, const int* in_sizes, int n_in,
                              void* d_out, int out_size, void* d_ws, size_t ws_size,
                              hipStream_t stream) {
    const float* x      = (const float*)d_in[0];
    const float* w_qkv  = (const float*)d_in[1];
    const float* b_qkv  = (const float*)d_in[2];
    const float* scale  = (const float*)d_in[3];
    const float* w_proj = (const float*)d_in[4];
    const float* b_proj = (const float*)d_in[5];
    float* out = (float*)d_out;

    const int B = 32, N = 577, C = 768, H = 12;
    const int M  = B * N;     // 18464
    const int C3 = 3 * C;     // 2304
    const int MB2 = (M + 255) / 256;   // 73

    short* qkvb   = (short*)d_ws;
    short* attn_o = qkvb + (size_t)M * C3;
    short* xb     = attn_o + (size_t)M * C;
    short* wqkvT  = xb + (size_t)M * C;
    short* wprojT = wqkvT + (size_t)C3 * C;
    short* vT     = wprojT + (size_t)C * C;

    dim3 blk(256);
    const long n4 = (long)M * C / 4;
    convert_bf16<<<dim3((n4 + 255) / 256), blk, 0, stream>>>(x, xb, n4);
    transpose_bf16<<<dim3(C3 / 32, C / 32), blk, 0, stream>>>(w_qkv, wqkvT, C, C3);
    transpose_bf16<<<dim3(C / 32, C / 32), blk, 0, stream>>>(w_proj, wprojT, C, C);

    gemm_bf16<short><<<dim3(MB2 * (C3 / 128)), blk, 0, stream>>>(
        xb, wqkvT, b_qkv, qkvb, M, C3, C, C3 / 128);

    transpose_v<<<dim3(B * H, 20), blk, 0, stream>>>(qkvb, vT);

    flash_attn<<<dim3(((N + 63) / 64) * H * B), blk, 0, stream>>>(qkvb, vT, scale, attn_o);

    gemm_bf16<float><<<dim3(MB2 * (C / 128)), blk, 0, stream>>>(
        attn_o, wprojT, b_proj, out, M, C, C, C / 128);
}